// Round 10
// baseline (206.137 us; speedup 1.0000x reference)
//
#include <hip/hip_runtime.h>
#include <math.h>

// Problem constants: B=2, S=2048, D=1024, H=16, HD=64
#define BB 2
#define SS 2048
#define DD 1024
#define HH 16
#define HD 64
#define MM (BB * SS)   // 4096 rows in flattened [B*S, D]

typedef __bf16 bf16;
typedef __attribute__((ext_vector_type(8))) __bf16 bf16x8;
typedef __attribute__((ext_vector_type(4))) __bf16 bf16x4;
typedef __attribute__((ext_vector_type(4))) float f32x4;

// async global->LDS, 16 B per lane. lds dest = wave-uniform base + lane*16.
__device__ __forceinline__ void gld_lds16(const void* g, void* l) {
    __builtin_amdgcn_global_load_lds(
        (const __attribute__((address_space(1))) void*)g,
        (__attribute__((address_space(3))) void*)l, 16, 0, 0);
}

// ---------------------------------------------------------------------------
// prep: z<4 -> transpose+cast weight z (W[K,N] fp32 -> Wt[N,K] bf16);
//       z>=4 -> flat cast x fp32 -> bf16 (8 elems/thread). grid (32,32,6)
// ---------------------------------------------------------------------------
__global__ __launch_bounds__(256) void prep(
    const float* __restrict__ x,
    const float* __restrict__ W0, const float* __restrict__ W1,
    const float* __restrict__ W2, const float* __restrict__ W3,
    bf16* __restrict__ xb, bf16* __restrict__ Wt)
{
    __shared__ float tile[32][33];
    const int z = blockIdx.z;
    if (z < 4) {
        const float* W = (z == 0) ? W0 : (z == 1) ? W1 : (z == 2) ? W2 : W3;
        bf16* O = Wt + (size_t)z * DD * DD;
        const int tx = threadIdx.x & 31, ty = threadIdx.x >> 5;
        const int k0 = blockIdx.y * 32, n0 = blockIdx.x * 32;
#pragma unroll
        for (int i = 0; i < 4; ++i)
            tile[ty + i * 8][tx] = W[(size_t)(k0 + ty + i * 8) * DD + n0 + tx];
        __syncthreads();
#pragma unroll
        for (int i = 0; i < 4; ++i)
            O[(size_t)(n0 + ty + i * 8) * DD + k0 + tx] = (bf16)tile[tx][ty + i * 8];
    } else {
        const int lb = (z - 4) * 1024 + blockIdx.y * 32 + blockIdx.x;
        const size_t i = ((size_t)lb * 256 + threadIdx.x) * 8;
        const float4 a = *(const float4*)(x + i);
        const float4 b = *(const float4*)(x + i + 4);
        bf16x8 o;
        o[0] = (bf16)a.x; o[1] = (bf16)a.y; o[2] = (bf16)a.z; o[3] = (bf16)a.w;
        o[4] = (bf16)b.x; o[5] = (bf16)b.y; o[6] = (bf16)b.z; o[7] = (bf16)b.w;
        *(bf16x8*)(xb + i) = o;
    }
}

// ---------------------------------------------------------------------------
// MFMA GEMM core, BK=64 (R8 version — measured best).
// ---------------------------------------------------------------------------
template<bool SWAP>
__device__ __forceinline__ void mfma_core(
    const bf16* __restrict__ A, const bf16* __restrict__ Bt,
    int bm, int bn, int K, bf16* As, bf16* Bs, f32x4 (&acc)[4][4])
{
    const int t = threadIdx.x;
    const int w = t >> 6;
    const int l16 = t & 15, quad = (t >> 4) & 3;
    const int wr = w >> 1, wc = w & 1;
    const int r0 = t >> 3;
    const int cs = t & 7;

    for (int k0 = 0; k0 < K; k0 += 64) {
#pragma unroll
        for (int j = 0; j < 4; ++j) {
            const int row = j * 32 + r0;
            const int c = (cs - row) & 7;
            gld_lds16(A  + (size_t)(bm + row) * K + k0 + c * 8,
                      As + (j * 32 + w * 8) * 64);
            gld_lds16(Bt + (size_t)(bn + row) * K + k0 + c * 8,
                      Bs + (j * 32 + w * 8) * 64);
        }
        __syncthreads();

#pragma unroll
        for (int h = 0; h < 2; ++h) {
            bf16x8 af[4], bv[4];
#pragma unroll
            for (int i = 0; i < 4; ++i) {
                const int ra = wr * 64 + i * 16 + l16;
                af[i] = *(const bf16x8*)(As + ra * 64 + (((h * 4 + quad) + ra) & 7) * 8);
                const int rb = wc * 64 + i * 16 + l16;
                bv[i] = *(const bf16x8*)(Bs + rb * 64 + (((h * 4 + quad) + rb) & 7) * 8);
            }
#pragma unroll
            for (int mi = 0; mi < 4; ++mi)
#pragma unroll
                for (int ni = 0; ni < 4; ++ni)
                    acc[mi][ni] = SWAP
                        ? __builtin_amdgcn_mfma_f32_16x16x32_bf16(bv[mi], af[ni], acc[mi][ni], 0, 0, 0)
                        : __builtin_amdgcn_mfma_f32_16x16x32_bf16(af[mi], bv[ni], acc[mi][ni], 0, 0, 0);
        }
        __syncthreads();
    }
}

// ---------------------------------------------------------------------------
// QKV fused GEMM (R8 3-D grid — measured best): z=0 Q, z=1 K, z=2 V^T
// ---------------------------------------------------------------------------
__global__ __launch_bounds__(256) void gemm_qkv(
    const bf16* __restrict__ xb, const bf16* __restrict__ Wt,
    bf16* __restrict__ Qb, bf16* __restrict__ Kb, bf16* __restrict__ Vb)
{
    __shared__ __align__(16) bf16 As[128 * 64];
    __shared__ __align__(16) bf16 Bs[128 * 64];
    const int bm = blockIdx.y * 128, bn = blockIdx.x * 128, z = blockIdx.z;
    const bf16* Wz = Wt + (size_t)z * DD * DD;

    const int t = threadIdx.x;
    const int w = t >> 6, l16 = t & 15, quad = (t >> 4) & 3;
    const int wr = w >> 1, wc = w & 1;

    f32x4 acc[4][4] = {};
    if (z < 2) {
        mfma_core<true>(xb, Wz, bm, bn, DD, As, Bs, acc);
        bf16* outp = (z == 0) ? Qb : Kb;
#pragma unroll
        for (int mi = 0; mi < 4; ++mi) {
            const int feat = bn + wc * 64 + mi * 16 + quad * 4;
            const int h = feat >> 6, hd = feat & 63;
#pragma unroll
            for (int ni = 0; ni < 4; ++ni) {
                const int tok = bm + wr * 64 + ni * 16 + l16;
                const int b = tok >> 11, s = tok & (SS - 1);
                bf16x4 o;
#pragma unroll
                for (int r = 0; r < 4; ++r) o[r] = (bf16)acc[mi][ni][r];
                *(bf16x4*)(outp + ((size_t)((b * HH + h) * SS + s)) * HD + hd) = o;
            }
        }
    } else {
        mfma_core<false>(xb, Wz, bm, bn, DD, As, Bs, acc);
#pragma unroll
        for (int mi = 0; mi < 4; ++mi) {
            const int tok0 = bm + wr * 64 + mi * 16 + quad * 4;
            const int b = tok0 >> 11, s0 = tok0 & (SS - 1);
#pragma unroll
            for (int ni = 0; ni < 4; ++ni) {
                const int feat = bn + wc * 64 + ni * 16 + l16;
                const int h = feat >> 6, hd = feat & 63;
                bf16x4 o;
#pragma unroll
                for (int r = 0; r < 4; ++r) o[r] = (bf16)acc[mi][ni][r];
                *(bf16x4*)(Vb + ((size_t)((b * HH + h) * HD + hd)) * SS + s0) = o;
            }
        }
    }
}

// ---------------------------------------------------------------------------
// Output projection, 128x64 tiles -> 512 blocks (2/CU; was 256 = 1/CU).
// ctx(bf16) @ Wo^T + bo -> fp32 [M, D]. SWAP orientation -> float4 stores.
// ---------------------------------------------------------------------------
__global__ __launch_bounds__(256) void gemm_out(
    const bf16* __restrict__ ctx, const bf16* __restrict__ Wto,
    const float* __restrict__ bias, float* __restrict__ out)
{
    __shared__ __align__(16) bf16 As[128 * 64];   // 16 KB
    __shared__ __align__(16) bf16 Bs[64 * 64];    //  8 KB

    const int L = blockIdx.x;
    const int bm = (L >> 4) * 128;
    const int bn = (L & 15) * 64;

    const int t = threadIdx.x;
    const int w = t >> 6, l16 = t & 15, quad = (t >> 4) & 3;
    const int wr = w >> 1, wc = w & 1;
    const int r0 = t >> 3, cs = t & 7;

    f32x4 acc[2][4] = {};   // [feat-sub][tok-sub]

    for (int k0 = 0; k0 < DD; k0 += 64) {
#pragma unroll
        for (int j = 0; j < 4; ++j) {
            const int row = j * 32 + r0;
            const int c = (cs - row) & 7;
            gld_lds16(ctx + (size_t)(bm + row) * DD + k0 + c * 8,
                      As + (j * 32 + w * 8) * 64);
        }
#pragma unroll
        for (int j = 0; j < 2; ++j) {
            const int row = j * 32 + r0;
            const int c = (cs - row) & 7;
            gld_lds16(Wto + (size_t)(bn + row) * DD + k0 + c * 8,
                      Bs + (j * 32 + w * 8) * 64);
        }
        __syncthreads();

#pragma unroll
        for (int h = 0; h < 2; ++h) {
            bf16x8 af[4], bv[2];
#pragma unroll
            for (int i = 0; i < 4; ++i) {
                const int ra = wr * 64 + i * 16 + l16;
                af[i] = *(const bf16x8*)(As + ra * 64 + (((h * 4 + quad) + ra) & 7) * 8);
            }
#pragma unroll
            for (int i = 0; i < 2; ++i) {
                const int rb = wc * 32 + i * 16 + l16;
                bv[i] = *(const bf16x8*)(Bs + rb * 64 + (((h * 4 + quad) + rb) & 7) * 8);
            }
#pragma unroll
            for (int fi = 0; fi < 2; ++fi)
#pragma unroll
                for (int ti = 0; ti < 4; ++ti)
                    acc[fi][ti] = __builtin_amdgcn_mfma_f32_16x16x32_bf16(
                        bv[fi], af[ti], acc[fi][ti], 0, 0, 0);
        }
        __syncthreads();
    }

#pragma unroll
    for (int fi = 0; fi < 2; ++fi) {
        const int feat = bn + wc * 32 + fi * 16 + quad * 4;
        const float4 bb = *(const float4*)(bias + feat);
#pragma unroll
        for (int ti = 0; ti < 4; ++ti) {
            const int tok = bm + wr * 64 + ti * 16 + l16;
            float4 o;
            o.x = acc[fi][ti][0] + bb.x;
            o.y = acc[fi][ti][1] + bb.y;
            o.z = acc[fi][ti][2] + bb.z;
            o.w = acc[fi][ti][3] + bb.w;
            *(float4*)(out + (size_t)tok * DD + feat) = o;
        }
    }
}

// ---------------------------------------------------------------------------
// Flash attention v6: 128 queries/block (4 waves x 32 q), 64-key tiles,
// monolithic (split-K reverted — R8 ledger showed combine cost > chain gain).
// Staging traffic halves vs R6 (each staged K/V tile serves 2x the queries);
// each wave runs 2 q-subtiles -> 32 MFMA per staged tile per wave.
// Waves skip fully-masked tiles (guard between barriers).
//   - S^T = K.Q^T so softmax columns == q (per-lane stats, no broadcast)
//   - static-max softmax (scores bounded; R5 analysis)
//   - K/V rot-swizzled in LDS, double-buffered; LDS 50 KB -> 3 blocks/CU
// grid 512: bh = L&31 (XCD locality), qg = 15-(L>>5) heavy-first
// ---------------------------------------------------------------------------
#define PROWS 72
__global__ __launch_bounds__(256) void attn_flash(
    const bf16* __restrict__ Q, const bf16* __restrict__ K,
    const bf16* __restrict__ Vt, bf16* __restrict__ ctx)
{
    __shared__ __align__(16) bf16 Ks[2][64 * 64];    // [key][d], rot-swizzled
    __shared__ __align__(16) bf16 Vs[2][64 * 64];    // [d][key], rot-swizzled
    __shared__ __align__(16) bf16 Pl[4][32 * PROWS]; // per-wave P[q][key]

    const int t = threadIdx.x;
    const int w = t >> 6;
    const int lane = t & 63;
    const int l16 = lane & 15, quad = lane >> 4;

    const int L  = blockIdx.x;
    const int bh = L & 31;                 // XCD locality
    const int qg = 15 - (L >> 5);          // heavy 128-q groups first
    const int q0w = qg * 128 + w * 32;     // this wave's first query

    const bf16* Qp = Q  + ((size_t)bh * SS + q0w) * HD;
    const bf16* Kp = K  + (size_t)bh * SS * HD;
    const bf16* Vp = Vt + (size_t)bh * HD * SS;
    bf16* Pw = &Pl[w][0];

    // Q B-fragments: 2 q-subtiles x 2 d-chunks
    bf16x8 bQ[2][2];
#pragma unroll
    for (int qs = 0; qs < 2; ++qs)
#pragma unroll
        for (int c = 0; c < 2; ++c)
            bQ[qs][c] = *(const bf16x8*)(Qp + (qs * 16 + l16) * HD + c * 32 + quad * 8);

    f32x4 accO[4][2] = {};   // [d-sub][q-sub]
    float Lr[2] = {0.f, 0.f};
    const float cl2 = 0.125f * 1.44269504f;   // scale * log2(e)

    const int r8 = lane >> 3, cs = lane & 7;
    const int nkt = 2 * qg + 2;   // 64-key tiles covering 0..qg*128+127

    // prologue: stage tile 0 into buffer 0 (8 regions of 8 rows)
#pragma unroll
    for (int j = 0; j < 2; ++j) {
        const int region = w * 2 + j;
        const int row = region * 8 + r8;
        const int c = (cs - row) & 7;
        gld_lds16(Kp + (size_t)row * HD + c * 8, &Ks[0][region * 512]);
        gld_lds16(Vp + (size_t)row * SS + c * 8, &Vs[0][region * 512]);
    }

    for (int kt = 0; kt < nkt; ++kt) {
        const int kb = kt * 64;
        const int buf = kt & 1;
        __syncthreads();   // staging of `buf` complete

        if (kt + 1 < nkt) {
            const int kb2 = kb + 64;
#pragma unroll
            for (int j = 0; j < 2; ++j) {
                const int region = w * 2 + j;
                const int row = region * 8 + r8;
                const int c = (cs - row) & 7;
                gld_lds16(Kp + (size_t)(kb2 + row) * HD + c * 8, &Ks[buf ^ 1][region * 512]);
                gld_lds16(Vp + (size_t)row * SS + kb2 + c * 8, &Vs[buf ^ 1][region * 512]);
            }
        }

        // skip tiles entirely above this wave's query range (all-masked)
        if (kb <= q0w + 31) {
            const bf16* Kbuf = &Ks[buf][0];
            const bf16* Vbuf = &Vs[buf][0];

            // ---- QK^T -> St[key-sub][q-sub] --------------------------------
            f32x4 St[4][2] = {};
#pragma unroll
            for (int mi = 0; mi < 4; ++mi) {
                const int row = mi * 16 + l16;
                const bf16x8 a0 = *(const bf16x8*)(Kbuf + row * 64 + ((quad + row) & 7) * 8);
                const bf16x8 a1 = *(const bf16x8*)(Kbuf + row * 64 + ((quad + 4 + row) & 7) * 8);
#pragma unroll
                for (int qs = 0; qs < 2; ++qs) {
                    St[mi][qs] = __builtin_amdgcn_mfma_f32_16x16x32_bf16(a0, bQ[qs][0], St[mi][qs], 0, 0, 0);
                    St[mi][qs] = __builtin_amdgcn_mfma_f32_16x16x32_bf16(a1, bQ[qs][1], St[mi][qs], 0, 0, 0);
                }
            }

            // ---- causal mask (tiles crossing the diagonal) -----------------
            if (kb + 63 > q0w) {
#pragma unroll
                for (int qs = 0; qs < 2; ++qs) {
                    const int qrow = q0w + qs * 16 + l16;
#pragma unroll
                    for (int mi = 0; mi < 4; ++mi)
#pragma unroll
                        for (int r = 0; r < 4; ++r)
                            if (kb + mi * 16 + quad * 4 + r > qrow) St[mi][qs][r] = -1e30f;
                }
            }

            // ---- static-max softmax ----------------------------------------
#pragma unroll
            for (int qs = 0; qs < 2; ++qs) {
                float rs = 0.f;
#pragma unroll
                for (int mi = 0; mi < 4; ++mi) {
                    bf16x4 pk;
#pragma unroll
                    for (int r = 0; r < 4; ++r) {
                        const float p = exp2f(St[mi][qs][r] * cl2);
                        rs += p;
                        pk[r] = (bf16)p;
                    }
                    *(bf16x4*)(Pw + (qs * 16 + l16) * PROWS + mi * 16 + quad * 4) = pk;
                }
                rs += __shfl_xor(rs, 16);
                rs += __shfl_xor(rs, 32);
                Lr[qs] += rs;
            }

            // ---- PV: O^T[d][q] += V^T[d][key] . P^T[key][q] ----------------
#pragma unroll
            for (int kc = 0; kc < 2; ++kc) {
                bf16x8 bP[2];
#pragma unroll
                for (int qs = 0; qs < 2; ++qs)
                    bP[qs] = *(const bf16x8*)(Pw + (qs * 16 + l16) * PROWS + kc * 32 + quad * 8);
#pragma unroll
                for (int mi = 0; mi < 4; ++mi) {
                    const int row = mi * 16 + l16;
                    const bf16x8 aV = *(const bf16x8*)(
                        Vbuf + row * 64 + (((kc * 4 + quad) + row) & 7) * 8);
#pragma unroll
                    for (int qs = 0; qs < 2; ++qs)
                        accO[mi][qs] = __builtin_amdgcn_mfma_f32_16x16x32_bf16(
                            aV, bP[qs], accO[mi][qs], 0, 0, 0);
                }
            }
        }
    }

    // ---- epilogue: divide by denom, write ctx (bf16, head-major cols) ------
    const int b = bh >> 4, h = bh & (HH - 1);
#pragma unroll
    for (int qs = 0; qs < 2; ++qs) {
        const float rinv = 1.0f / Lr[qs];
        bf16* op = ctx + ((size_t)(b * SS + q0w + qs * 16 + l16)) * DD + h * HD;
#pragma unroll
        for (int mi = 0; mi < 4; ++mi) {
            bf16x4 o;
#pragma unroll
            for (int r = 0; r < 4; ++r) o[r] = (bf16)(accO[mi][qs][r] * rinv);
            *(bf16x4*)(op + mi * 16 + quad * 4) = o;
        }
    }
}

// ---------------------------------------------------------------------------
extern "C" void kernel_launch(void* const* d_in, const int* in_sizes, int n_in,
                              void* d_out, int out_size, void* d_ws, size_t ws_size,
                              hipStream_t stream)
{
    const float* x  = (const float*)d_in[0];
    const float* Wq = (const float*)d_in[1];
    const float* Wk = (const float*)d_in[2];
    const float* Wv = (const float*)d_in[3];
    const float* Wo = (const float*)d_in[4];
    const float* bo = (const float*)d_in[5];
    float* out = (float*)d_out;

    const size_t chunk = (size_t)MM * DD;
    bf16* xb  = (bf16*)d_ws;
    bf16* Wt  = xb + chunk;
    bf16* Qb  = Wt + 4 * (size_t)DD * DD;
    bf16* Kb  = Qb + chunk;
    bf16* Vb  = Kb + chunk;
    bf16* ctx = Vb + chunk;

    prep<<<dim3(32, 32, 6), dim3(256), 0, stream>>>(x, Wq, Wk, Wv, Wo, xb, Wt);

    gemm_qkv<<<dim3(DD / 128, MM / 128, 3), dim3(256), 0, stream>>>(xb, Wt, Qb, Kb, Vb);

    attn_flash<<<dim3(512), dim3(256), 0, stream>>>(Qb, Kb, Vb, ctx);

    gemm_out<<<dim3(512), dim3(256), 0, stream>>>(
        ctx, Wt + 3 * (size_t)DD * DD, bo, out);
}

// Round 11
// 196.444 us; speedup vs baseline: 1.0493x; 1.0493x over previous
//
#include <hip/hip_runtime.h>
#include <math.h>

// Problem constants: B=2, S=2048, D=1024, H=16, HD=64
#define BB 2
#define SS 2048
#define DD 1024
#define HH 16
#define HD 64
#define MM (BB * SS)   // 4096 rows in flattened [B*S, D]

typedef __bf16 bf16;
typedef __attribute__((ext_vector_type(8))) __bf16 bf16x8;
typedef __attribute__((ext_vector_type(4))) __bf16 bf16x4;
typedef __attribute__((ext_vector_type(4))) float f32x4;

// async global->LDS, 16 B per lane. lds dest = wave-uniform base + lane*16.
__device__ __forceinline__ void gld_lds16(const void* g, void* l) {
    __builtin_amdgcn_global_load_lds(
        (const __attribute__((address_space(1))) void*)g,
        (__attribute__((address_space(3))) void*)l, 16, 0, 0);
}

// ---------------------------------------------------------------------------
// prep: z<4 -> transpose+cast weight z (W[K,N] fp32 -> Wt[N,K] bf16);
//       z>=4 -> flat cast x fp32 -> bf16 (8 elems/thread). grid (32,32,6)
// ---------------------------------------------------------------------------
__global__ __launch_bounds__(256) void prep(
    const float* __restrict__ x,
    const float* __restrict__ W0, const float* __restrict__ W1,
    const float* __restrict__ W2, const float* __restrict__ W3,
    bf16* __restrict__ xb, bf16* __restrict__ Wt)
{
    __shared__ float tile[32][33];
    const int z = blockIdx.z;
    if (z < 4) {
        const float* W = (z == 0) ? W0 : (z == 1) ? W1 : (z == 2) ? W2 : W3;
        bf16* O = Wt + (size_t)z * DD * DD;
        const int tx = threadIdx.x & 31, ty = threadIdx.x >> 5;
        const int k0 = blockIdx.y * 32, n0 = blockIdx.x * 32;
#pragma unroll
        for (int i = 0; i < 4; ++i)
            tile[ty + i * 8][tx] = W[(size_t)(k0 + ty + i * 8) * DD + n0 + tx];
        __syncthreads();
#pragma unroll
        for (int i = 0; i < 4; ++i)
            O[(size_t)(n0 + ty + i * 8) * DD + k0 + tx] = (bf16)tile[tx][ty + i * 8];
    } else {
        const int lb = (z - 4) * 1024 + blockIdx.y * 32 + blockIdx.x;
        const size_t i = ((size_t)lb * 256 + threadIdx.x) * 8;
        const float4 a = *(const float4*)(x + i);
        const float4 b = *(const float4*)(x + i + 4);
        bf16x8 o;
        o[0] = (bf16)a.x; o[1] = (bf16)a.y; o[2] = (bf16)a.z; o[3] = (bf16)a.w;
        o[4] = (bf16)b.x; o[5] = (bf16)b.y; o[6] = (bf16)b.z; o[7] = (bf16)b.w;
        *(bf16x8*)(xb + i) = o;
    }
}

// ---------------------------------------------------------------------------
// MFMA GEMM core, BK=64 (R8 version — measured best).
// ---------------------------------------------------------------------------
template<bool SWAP>
__device__ __forceinline__ void mfma_core(
    const bf16* __restrict__ A, const bf16* __restrict__ Bt,
    int bm, int bn, int K, bf16* As, bf16* Bs, f32x4 (&acc)[4][4])
{
    const int t = threadIdx.x;
    const int w = t >> 6;
    const int l16 = t & 15, quad = (t >> 4) & 3;
    const int wr = w >> 1, wc = w & 1;
    const int r0 = t >> 3;
    const int cs = t & 7;

    for (int k0 = 0; k0 < K; k0 += 64) {
#pragma unroll
        for (int j = 0; j < 4; ++j) {
            const int row = j * 32 + r0;
            const int c = (cs - row) & 7;
            gld_lds16(A  + (size_t)(bm + row) * K + k0 + c * 8,
                      As + (j * 32 + w * 8) * 64);
            gld_lds16(Bt + (size_t)(bn + row) * K + k0 + c * 8,
                      Bs + (j * 32 + w * 8) * 64);
        }
        __syncthreads();

#pragma unroll
        for (int h = 0; h < 2; ++h) {
            bf16x8 af[4], bv[4];
#pragma unroll
            for (int i = 0; i < 4; ++i) {
                const int ra = wr * 64 + i * 16 + l16;
                af[i] = *(const bf16x8*)(As + ra * 64 + (((h * 4 + quad) + ra) & 7) * 8);
                const int rb = wc * 64 + i * 16 + l16;
                bv[i] = *(const bf16x8*)(Bs + rb * 64 + (((h * 4 + quad) + rb) & 7) * 8);
            }
#pragma unroll
            for (int mi = 0; mi < 4; ++mi)
#pragma unroll
                for (int ni = 0; ni < 4; ++ni)
                    acc[mi][ni] = SWAP
                        ? __builtin_amdgcn_mfma_f32_16x16x32_bf16(bv[mi], af[ni], acc[mi][ni], 0, 0, 0)
                        : __builtin_amdgcn_mfma_f32_16x16x32_bf16(af[mi], bv[ni], acc[mi][ni], 0, 0, 0);
        }
        __syncthreads();
    }
}

// ---------------------------------------------------------------------------
// QKV fused GEMM (R8 3-D grid — measured best): z=0 Q, z=1 K, z=2 V^T
// ---------------------------------------------------------------------------
__global__ __launch_bounds__(256) void gemm_qkv(
    const bf16* __restrict__ xb, const bf16* __restrict__ Wt,
    bf16* __restrict__ Qb, bf16* __restrict__ Kb, bf16* __restrict__ Vb)
{
    __shared__ __align__(16) bf16 As[128 * 64];
    __shared__ __align__(16) bf16 Bs[128 * 64];
    const int bm = blockIdx.y * 128, bn = blockIdx.x * 128, z = blockIdx.z;
    const bf16* Wz = Wt + (size_t)z * DD * DD;

    const int t = threadIdx.x;
    const int w = t >> 6, l16 = t & 15, quad = (t >> 4) & 3;
    const int wr = w >> 1, wc = w & 1;

    f32x4 acc[4][4] = {};
    if (z < 2) {
        mfma_core<true>(xb, Wz, bm, bn, DD, As, Bs, acc);
        bf16* outp = (z == 0) ? Qb : Kb;
#pragma unroll
        for (int mi = 0; mi < 4; ++mi) {
            const int feat = bn + wc * 64 + mi * 16 + quad * 4;
            const int h = feat >> 6, hd = feat & 63;
#pragma unroll
            for (int ni = 0; ni < 4; ++ni) {
                const int tok = bm + wr * 64 + ni * 16 + l16;
                const int b = tok >> 11, s = tok & (SS - 1);
                bf16x4 o;
#pragma unroll
                for (int r = 0; r < 4; ++r) o[r] = (bf16)acc[mi][ni][r];
                *(bf16x4*)(outp + ((size_t)((b * HH + h) * SS + s)) * HD + hd) = o;
            }
        }
    } else {
        mfma_core<false>(xb, Wz, bm, bn, DD, As, Bs, acc);
#pragma unroll
        for (int mi = 0; mi < 4; ++mi) {
            const int tok0 = bm + wr * 64 + mi * 16 + quad * 4;
            const int b = tok0 >> 11, s0 = tok0 & (SS - 1);
#pragma unroll
            for (int ni = 0; ni < 4; ++ni) {
                const int feat = bn + wc * 64 + ni * 16 + l16;
                const int h = feat >> 6, hd = feat & 63;
                bf16x4 o;
#pragma unroll
                for (int r = 0; r < 4; ++r) o[r] = (bf16)acc[mi][ni][r];
                *(bf16x4*)(Vb + ((size_t)((b * HH + h) * HD + hd)) * SS + s0) = o;
            }
        }
    }
}

// ---------------------------------------------------------------------------
// Output projection, 128x64 tiles -> 512 blocks (2/CU).
// ctx(bf16) @ Wo^T + bo -> fp32 [M, D]. SWAP orientation -> float4 stores.
// ---------------------------------------------------------------------------
__global__ __launch_bounds__(256) void gemm_out(
    const bf16* __restrict__ ctx, const bf16* __restrict__ Wto,
    const float* __restrict__ bias, float* __restrict__ out)
{
    __shared__ __align__(16) bf16 As[128 * 64];   // 16 KB
    __shared__ __align__(16) bf16 Bs[64 * 64];    //  8 KB

    const int L = blockIdx.x;
    const int bm = (L >> 4) * 128;
    const int bn = (L & 15) * 64;

    const int t = threadIdx.x;
    const int w = t >> 6, l16 = t & 15, quad = (t >> 4) & 3;
    const int wr = w >> 1, wc = w & 1;
    const int r0 = t >> 3, cs = t & 7;

    f32x4 acc[2][4] = {};   // [feat-sub][tok-sub]

    for (int k0 = 0; k0 < DD; k0 += 64) {
#pragma unroll
        for (int j = 0; j < 4; ++j) {
            const int row = j * 32 + r0;
            const int c = (cs - row) & 7;
            gld_lds16(ctx + (size_t)(bm + row) * DD + k0 + c * 8,
                      As + (j * 32 + w * 8) * 64);
        }
#pragma unroll
        for (int j = 0; j < 2; ++j) {
            const int row = j * 32 + r0;
            const int c = (cs - row) & 7;
            gld_lds16(Wto + (size_t)(bn + row) * DD + k0 + c * 8,
                      Bs + (j * 32 + w * 8) * 64);
        }
        __syncthreads();

#pragma unroll
        for (int h = 0; h < 2; ++h) {
            bf16x8 af[4], bv[2];
#pragma unroll
            for (int i = 0; i < 4; ++i) {
                const int ra = wr * 64 + i * 16 + l16;
                af[i] = *(const bf16x8*)(As + ra * 64 + (((h * 4 + quad) + ra) & 7) * 8);
            }
#pragma unroll
            for (int i = 0; i < 2; ++i) {
                const int rb = wc * 32 + i * 16 + l16;
                bv[i] = *(const bf16x8*)(Bs + rb * 64 + (((h * 4 + quad) + rb) & 7) * 8);
            }
#pragma unroll
            for (int fi = 0; fi < 2; ++fi)
#pragma unroll
                for (int ti = 0; ti < 4; ++ti)
                    acc[fi][ti] = __builtin_amdgcn_mfma_f32_16x16x32_bf16(
                        bv[fi], af[ti], acc[fi][ti], 0, 0, 0);
        }
        __syncthreads();
    }

#pragma unroll
    for (int fi = 0; fi < 2; ++fi) {
        const int feat = bn + wc * 32 + fi * 16 + quad * 4;
        const float4 bb = *(const float4*)(bias + feat);
#pragma unroll
        for (int ti = 0; ti < 4; ++ti) {
            const int tok = bm + wr * 64 + ti * 16 + l16;
            float4 o;
            o.x = acc[fi][ti][0] + bb.x;
            o.y = acc[fi][ti][1] + bb.y;
            o.z = acc[fi][ti][2] + bb.z;
            o.w = acc[fi][ti][3] + bb.w;
            *(float4*)(out + (size_t)tok * DD + feat) = o;
        }
    }
}

// ---------------------------------------------------------------------------
// Flash attention v7: CAUSAL-PAIRED blocks for perfect load balance.
// Block owns query groups gh=31-pr (heavy) and gl=pr (light), 4 waves x 16q
// per group. Keys staged ONCE for the union range (gh+1 tiles); light group
// computes only while kt <= gl. Every block does (gh+1)+(gl+1) = 33 equal
// tile-compute units -> uniform makespan, no causal tail. Grid 512 = 2
// resident blocks/CU (LDS 50 KB), zero dispatch waves.
// Inner loop = R6 (measured best): S^T = K.Q^T, static-max softmax,
// rot-swizzled double-buffered K/V, per-wave P in LDS.
// ---------------------------------------------------------------------------
#define PROWS 72
template<int NG>
__device__ __forceinline__ void attn_tile(
    const bf16* __restrict__ Kbuf, const bf16* __restrict__ Vbuf,
    bf16* __restrict__ Pw, const bf16x8 (&bQ)[2][2], const int (&qbase)[2],
    int kb, int l16, int quad, f32x4 (&accO)[4][2], float (&Lr)[2], float cl2)
{
    // ---- QK^T -> St[key-sub][group] ---------------------------------------
    f32x4 St[4][NG] = {};
#pragma unroll
    for (int mi = 0; mi < 4; ++mi) {
        const int row = mi * 16 + l16;
        const bf16x8 a0 = *(const bf16x8*)(Kbuf + row * 64 + ((quad + row) & 7) * 8);
        const bf16x8 a1 = *(const bf16x8*)(Kbuf + row * 64 + ((quad + 4 + row) & 7) * 8);
#pragma unroll
        for (int qs = 0; qs < NG; ++qs) {
            St[mi][qs] = __builtin_amdgcn_mfma_f32_16x16x32_bf16(a0, bQ[qs][0], St[mi][qs], 0, 0, 0);
            St[mi][qs] = __builtin_amdgcn_mfma_f32_16x16x32_bf16(a1, bQ[qs][1], St[mi][qs], 0, 0, 0);
        }
    }

    // ---- causal mask (only tiles crossing the group's diagonal) -----------
#pragma unroll
    for (int qs = 0; qs < NG; ++qs) {
        if (kb + 63 > qbase[qs]) {
            const int qrow = qbase[qs] + l16;
#pragma unroll
            for (int mi = 0; mi < 4; ++mi)
#pragma unroll
                for (int r = 0; r < 4; ++r)
                    if (kb + mi * 16 + quad * 4 + r > qrow) St[mi][qs][r] = -1e30f;
        }
    }

    // ---- static-max softmax: p = exp2(s*cl2), L += sum --------------------
#pragma unroll
    for (int qs = 0; qs < NG; ++qs) {
        float rs = 0.f;
#pragma unroll
        for (int mi = 0; mi < 4; ++mi) {
            bf16x4 pk;
#pragma unroll
            for (int r = 0; r < 4; ++r) {
                const float p = exp2f(St[mi][qs][r] * cl2);
                rs += p;
                pk[r] = (bf16)p;
            }
            *(bf16x4*)(Pw + (qs * 16 + l16) * PROWS + mi * 16 + quad * 4) = pk;
        }
        rs += __shfl_xor(rs, 16);
        rs += __shfl_xor(rs, 32);
        Lr[qs] += rs;
    }

    // ---- PV: O^T[d][q] += V^T[d][key] . P^T[key][q] -----------------------
#pragma unroll
    for (int kc = 0; kc < 2; ++kc) {
        bf16x8 bP[NG];
#pragma unroll
        for (int qs = 0; qs < NG; ++qs)
            bP[qs] = *(const bf16x8*)(Pw + (qs * 16 + l16) * PROWS + kc * 32 + quad * 8);
#pragma unroll
        for (int mi = 0; mi < 4; ++mi) {
            const int row = mi * 16 + l16;
            const bf16x8 aV = *(const bf16x8*)(
                Vbuf + row * 64 + (((kc * 4 + quad) + row) & 7) * 8);
#pragma unroll
            for (int qs = 0; qs < NG; ++qs)
                accO[mi][qs] = __builtin_amdgcn_mfma_f32_16x16x32_bf16(
                    aV, bP[qs], accO[mi][qs], 0, 0, 0);
        }
    }
}

__global__ __launch_bounds__(256) void attn_flash(
    const bf16* __restrict__ Q, const bf16* __restrict__ K,
    const bf16* __restrict__ Vt, bf16* __restrict__ ctx)
{
    __shared__ __align__(16) bf16 Ks[2][64 * 64];    // [key][d], rot-swizzled
    __shared__ __align__(16) bf16 Vs[2][64 * 64];    // [d][key], rot-swizzled
    __shared__ __align__(16) bf16 Pl[4][32 * PROWS]; // per-wave P[q][key], 2 groups

    const int t = threadIdx.x;
    const int w = t >> 6;
    const int lane = t & 63;
    const int l16 = lane & 15, quad = lane >> 4;

    const int L  = blockIdx.x;
    const int bh = L & 31;                 // XCD locality
    const int pr = L >> 5;                 // pair index 0..15
    const int gh = 31 - pr;                // heavy query group
    const int gl = pr;                     // light query group
    int qbase[2];
    qbase[0] = gh * 64 + w * 16;           // heavy wave q0
    qbase[1] = gl * 64 + w * 16;           // light wave q0

    const bf16* Qp = Q  + (size_t)bh * SS * HD;
    const bf16* Kp = K  + (size_t)bh * SS * HD;
    const bf16* Vp = Vt + (size_t)bh * HD * SS;
    bf16* Pw = &Pl[w][0];

    // Q B-fragments: 2 groups x 2 d-chunks
    bf16x8 bQ[2][2];
#pragma unroll
    for (int qs = 0; qs < 2; ++qs)
#pragma unroll
        for (int c = 0; c < 2; ++c)
            bQ[qs][c] = *(const bf16x8*)(Qp + (size_t)(qbase[qs] + l16) * HD + c * 32 + quad * 8);

    f32x4 accO[4][2] = {};   // [d-sub][group]
    float Lr[2] = {0.f, 0.f};
    const float cl2 = 0.125f * 1.44269504f;   // scale * log2(e)

    const int r8 = lane >> 3, cs = lane & 7;
    const int nkt = gh + 1;   // key tiles for the union range

    // prologue: stage tile 0 into buffer 0 (8 regions of 8 rows)
#pragma unroll
    for (int j = 0; j < 2; ++j) {
        const int region = w * 2 + j;
        const int row = region * 8 + r8;
        const int c = (cs - row) & 7;
        gld_lds16(Kp + (size_t)row * HD + c * 8, &Ks[0][region * 512]);
        gld_lds16(Vp + (size_t)row * SS + c * 8, &Vs[0][region * 512]);
    }

    for (int kt = 0; kt < nkt; ++kt) {
        const int kb = kt * 64;
        const int buf = kt & 1;
        __syncthreads();   // staging of `buf` complete

        if (kt + 1 < nkt) {
            const int kb2 = kb + 64;
#pragma unroll
            for (int j = 0; j < 2; ++j) {
                const int region = w * 2 + j;
                const int row = region * 8 + r8;
                const int c = (cs - row) & 7;
                gld_lds16(Kp + (size_t)(kb2 + row) * HD + c * 8, &Ks[buf ^ 1][region * 512]);
                gld_lds16(Vp + (size_t)row * SS + kb2 + c * 8, &Vs[buf ^ 1][region * 512]);
            }
        }

        if (kt <= gl)
            attn_tile<2>(&Ks[buf][0], &Vs[buf][0], Pw, bQ, qbase, kb,
                         l16, quad, accO, Lr, cl2);
        else
            attn_tile<1>(&Ks[buf][0], &Vs[buf][0], Pw, bQ, qbase, kb,
                         l16, quad, accO, Lr, cl2);
    }

    // ---- epilogue: divide by denom, write ctx (bf16, head-major cols) ------
    const int b = bh >> 4, h = bh & (HH - 1);
#pragma unroll
    for (int qs = 0; qs < 2; ++qs) {
        const float rinv = 1.0f / Lr[qs];
        bf16* op = ctx + ((size_t)(b * SS + qbase[qs] + l16)) * DD + h * HD;
#pragma unroll
        for (int mi = 0; mi < 4; ++mi) {
            bf16x4 o;
#pragma unroll
            for (int r = 0; r < 4; ++r) o[r] = (bf16)(accO[mi][qs][r] * rinv);
            *(bf16x4*)(op + mi * 16 + quad * 4) = o;
        }
    }
}

// ---------------------------------------------------------------------------
extern "C" void kernel_launch(void* const* d_in, const int* in_sizes, int n_in,
                              void* d_out, int out_size, void* d_ws, size_t ws_size,
                              hipStream_t stream)
{
    const float* x  = (const float*)d_in[0];
    const float* Wq = (const float*)d_in[1];
    const float* Wk = (const float*)d_in[2];
    const float* Wv = (const float*)d_in[3];
    const float* Wo = (const float*)d_in[4];
    const float* bo = (const float*)d_in[5];
    float* out = (float*)d_out;

    const size_t chunk = (size_t)MM * DD;
    bf16* xb  = (bf16*)d_ws;
    bf16* Wt  = xb + chunk;
    bf16* Qb  = Wt + 4 * (size_t)DD * DD;
    bf16* Kb  = Qb + chunk;
    bf16* Vb  = Kb + chunk;
    bf16* ctx = Vb + chunk;

    prep<<<dim3(32, 32, 6), dim3(256), 0, stream>>>(x, Wq, Wk, Wv, Wo, xb, Wt);

    gemm_qkv<<<dim3(DD / 128, MM / 128, 3), dim3(256), 0, stream>>>(xb, Wt, Qb, Kb, Vb);

    attn_flash<<<dim3(512), dim3(256), 0, stream>>>(Qb, Kb, Vb, ctx);

    gemm_out<<<dim3(512), dim3(256), 0, stream>>>(
        ctx, Wt + 3 * (size_t)DD * DD, bo, out);
}